// Round 1
// baseline (360.857 us; speedup 1.0000x reference)
//
#include <hip/hip_runtime.h>
#include <math.h>

#define VV 32000
#define TT 128
#define EE 64
#define NN 1024

static constexpr float BOUND    = 1.41421356237309515f;   // sqrt(2)
static constexpr float LOG_SMIN = -2.30258509299404568f;  // log(0.1)
static constexpr float LOG_SMAX =  2.30258509299404568f;  // log(10)
static constexpr float LN2      =  0.69314718055994531f;
static constexpr float E_LOG2PI =  64.0f * 1.83787706640934548f; // E*log(2*pi)

// ---------------- kernel 0: clamp+exp the [T,E] context params ----------------
__global__ __launch_bounds__(256) void prep_ctx(const float* __restrict__ mu_c,
                                                const float* __restrict__ log_sigma_c,
                                                float* __restrict__ sc,
                                                float* __restrict__ mc) {
    int i = blockIdx.x * 256 + threadIdx.x;
    if (i < TT * EE) {
        float ls = log_sigma_c[i];
        ls = fminf(fmaxf(ls, LOG_SMIN), LOG_SMAX);
        sc[i] = expf(ls);
        float m = mu_c[i];
        mc[i] = fminf(fmaxf(m, -BOUND), BOUND);
    }
}

// ---------------- kernel 1: logits (transposed [T][V]) ----------------
// Block = 256 threads = 4 waves; block owns 64 consecutive v.
// Each thread holds its v's sigma/mu (64+64 floats) in VGPRs; sc/mc rows are
// wave-uniform -> scalar loads. det term via log2 of group-of-16 products.
__global__ __launch_bounds__(256) void logits_kernel(const float* __restrict__ mu,
                                                     const float* __restrict__ log_sigma,
                                                     const float* __restrict__ sc,
                                                     const float* __restrict__ mc,
                                                     float* __restrict__ logitsT) {
    __shared__ float stage_s[EE][65];  // +1 pad: transposed store, conflict-free
    __shared__ float stage_m[EE][65];
    const int tid = threadIdx.x;
    const int v0 = blockIdx.x * 64;

    // cooperative coalesced load of the 64x64 v-tile, transposed into LDS
    for (int k = tid; k < 64 * EE; k += 256) {
        int vi = k >> 6, e = k & 63;   // lanes -> consecutive e: coalesced global
        float ls = log_sigma[(v0 + vi) * EE + e];
        ls = fminf(fmaxf(ls, LOG_SMIN), LOG_SMAX);
        stage_s[e][vi] = expf(ls);
        float m = mu[(v0 + vi) * EE + e];
        stage_m[e][vi] = fminf(fmaxf(m, -BOUND), BOUND);
    }
    __syncthreads();

    const int lane = tid & 63;
    const int wv   = tid >> 6;

    float sv[EE], mv[EE];
#pragma unroll
    for (int e = 0; e < EE; e++) { sv[e] = stage_s[e][lane]; mv[e] = stage_m[e][lane]; }

    for (int t = wv; t < TT; t += 4) {
        const float* __restrict__ scr = sc + t * EE;  // wave-uniform -> s_load
        const float* __restrict__ mcr = mc + t * EE;
        float acc_l2 = 0.0f;
        float acc_q0 = 0.0f, acc_q1 = 0.0f;
#pragma unroll
        for (int g = 0; g < EE / 16; g++) {
            float prod = 1.0f;
#pragma unroll
            for (int k = 0; k < 16; k++) {
                int e = g * 16 + k;
                float s = sv[e] + scr[e];
                prod *= s;
                float d = mv[e] - mcr[e];
                float r = __builtin_amdgcn_rcpf(s);
                if (k & 1) acc_q1 += d * d * r; else acc_q0 += d * d * r;
            }
            acc_l2 += __log2f(prod);
        }
        float logit = -0.5f * (acc_l2 * LN2 + (acc_q0 + acc_q1) + E_LOG2PI);
        logitsT[t * VV + v0 + lane] = logit;
    }
}

// ---------------- kernel 2: per-topic softmax stats (max, 1/sumexp) ----------------
__global__ __launch_bounds__(256) void softmax_stats(const float* __restrict__ logitsT,
                                                     float* __restrict__ stats) {
    const int t = blockIdx.x;
    const int tid = threadIdx.x;
    const float* __restrict__ row = logitsT + (size_t)t * VV;

    __shared__ float red[4];
    __shared__ float red2[4];

    float m = -1e30f;
    for (int i = tid; i < VV; i += 256) m = fmaxf(m, row[i]);
#pragma unroll
    for (int off = 1; off < 64; off <<= 1) m = fmaxf(m, __shfl_xor(m, off));
    if ((tid & 63) == 0) red[tid >> 6] = m;
    __syncthreads();
    m = fmaxf(fmaxf(red[0], red[1]), fmaxf(red[2], red[3]));

    float s = 0.0f;
    for (int i = tid; i < VV; i += 256) s += __expf(row[i] - m);
#pragma unroll
    for (int off = 1; off < 64; off <<= 1) s += __shfl_xor(s, off);
    if ((tid & 63) == 0) red2[tid >> 6] = s;
    __syncthreads();
    if (tid == 0) {
        float tot = red2[0] + red2[1] + red2[2] + red2[3];
        stats[t] = m;
        stats[TT + t] = 1.0f / tot;
    }
}

// ---------------- kernel 3: out[V,N] = softmax(logits) @ x ----------------
// Block tile: 64 v x 256 n. Thread tile 8v x 8n (64 acc regs).
// w-tile computed on the fly into LDS; x served from L2 (256 MB total).
__global__ __launch_bounds__(256) void wx_matmul(const float* __restrict__ logitsT,
                                                 const float* __restrict__ stats,
                                                 const float* __restrict__ x,
                                                 float* __restrict__ out) {
    __shared__ float wT[TT][64];  // 32 KB
    const int tid = threadIdx.x;
    const int v0 = blockIdx.x * 64;
    const int n0 = blockIdx.y * 256;

    for (int i = tid; i < TT * 64; i += 256) {
        int t = i >> 6, v = i & 63;              // lanes -> consecutive v: coalesced
        float lg = logitsT[(size_t)t * VV + v0 + v];
        wT[t][v] = __expf(lg - stats[t]) * stats[TT + t];
    }
    __syncthreads();

    const int nt = tid & 31;   // 32 n-threads * 8 = 256 n
    const int vt = tid >> 5;   // 8 v-threads  * 8 = 64 v

    float acc[8][8];
#pragma unroll
    for (int i = 0; i < 8; i++)
#pragma unroll
        for (int j = 0; j < 8; j++) acc[i][j] = 0.0f;

    const float* __restrict__ xp = x + n0 + nt * 8;

    for (int t = 0; t < TT; t++) {
        float4 xa = *(const float4*)(xp + t * NN);
        float4 xb = *(const float4*)(xp + t * NN + 4);
        float4 wa = *(const float4*)(&wT[t][vt * 8]);
        float4 wb = *(const float4*)(&wT[t][vt * 8 + 4]);
        float wr[8] = {wa.x, wa.y, wa.z, wa.w, wb.x, wb.y, wb.z, wb.w};
        float xr[8] = {xa.x, xa.y, xa.z, xa.w, xb.x, xb.y, xb.z, xb.w};
#pragma unroll
        for (int i = 0; i < 8; i++)
#pragma unroll
            for (int j = 0; j < 8; j++) acc[i][j] += wr[i] * xr[j];
    }

#pragma unroll
    for (int i = 0; i < 8; i++) {
        float4 o0 = {acc[i][0], acc[i][1], acc[i][2], acc[i][3]};
        float4 o1 = {acc[i][4], acc[i][5], acc[i][6], acc[i][7]};
        float* dst = out + (size_t)(v0 + vt * 8 + i) * NN + n0 + nt * 8;
        *(float4*)dst = o0;
        *(float4*)(dst + 4) = o1;
    }
}

extern "C" void kernel_launch(void* const* d_in, const int* in_sizes, int n_in,
                              void* d_out, int out_size, void* d_ws, size_t ws_size,
                              hipStream_t stream) {
    const float* x           = (const float*)d_in[0];  // [T,N]
    const float* mu          = (const float*)d_in[1];  // [V,E]
    const float* log_sigma   = (const float*)d_in[2];  // [V,E]
    const float* mu_c        = (const float*)d_in[3];  // [T,E]
    const float* log_sigma_c = (const float*)d_in[4];  // [T,E]
    float* out = (float*)d_out;

    // ws layout (floats): logitsT [T*V] | sc [T*E] | mc [T*E] | stats [2*T]
    float* ws      = (float*)d_ws;
    float* logitsT = ws;
    float* sc      = ws + (size_t)TT * VV;
    float* mc      = sc + TT * EE;
    float* stats   = mc + TT * EE;

    prep_ctx<<<(TT * EE + 255) / 256, 256, 0, stream>>>(mu_c, log_sigma_c, sc, mc);
    logits_kernel<<<VV / 64, 256, 0, stream>>>(mu, log_sigma, sc, mc, logitsT);
    softmax_stats<<<TT, 256, 0, stream>>>(logitsT, stats);
    wx_matmul<<<dim3(VV / 64, NN / 256), 256, 0, stream>>>(logitsT, stats, x, out);
}

// Round 2
// 259.591 us; speedup vs baseline: 1.3901x; 1.3901x over previous
//
#include <hip/hip_runtime.h>
#include <math.h>

#define VV 32000
#define TT 128
#define EE 64
#define NN 1024

static constexpr float BOUND    = 1.41421356237309515f;   // sqrt(2)
static constexpr float LOG_SMIN = -2.30258509299404568f;  // log(0.1)
static constexpr float LOG_SMAX =  2.30258509299404568f;  // log(10)
static constexpr float LN2      =  0.69314718055994531f;
static constexpr float E_LOG2PI =  64.0f * 1.83787706640934548f; // E*log(2*pi)

typedef __attribute__((ext_vector_type(8)))  short short8;   // 8 bf16 = 4 VGPRs
typedef __attribute__((ext_vector_type(16))) float float16;  // MFMA 32x32 acc

static __device__ inline unsigned short f2bf(float f) {
    union { float f; unsigned u; } v; v.f = f;
    unsigned r = v.u + 0x7FFFu + ((v.u >> 16) & 1u);  // round-to-nearest-even
    return (unsigned short)(r >> 16);
}

// ---------------- kernel 0: clamp+exp the [T,E] context params ----------------
__global__ __launch_bounds__(256) void prep_ctx(const float* __restrict__ mu_c,
                                                const float* __restrict__ log_sigma_c,
                                                float* __restrict__ sc,
                                                float* __restrict__ mc) {
    int i = blockIdx.x * 256 + threadIdx.x;
    if (i < TT * EE) {
        float ls = log_sigma_c[i];
        ls = fminf(fmaxf(ls, LOG_SMIN), LOG_SMAX);
        sc[i] = expf(ls);
        float m = mu_c[i];
        mc[i] = fminf(fmaxf(m, -BOUND), BOUND);
    }
}

// ---------------- kernel 1: logits (transposed [T][V]) ----------------
// Block = 256 threads = 4 waves; block owns 64 consecutive v (one per lane).
// Per-lane sigma_v/mu_v in VGPRs (128 regs); sc/mc [128][64] preloaded to LDS
// (overlaid on the dead transpose-staging buffers) -> broadcast ds_read_b128
// co-issued with the VALU inner loop. det term via log2 of group-of-16 products.
__global__ __launch_bounds__(256) void logits_kernel(const float* __restrict__ mu,
                                                     const float* __restrict__ log_sigma,
                                                     const float* __restrict__ sc,
                                                     const float* __restrict__ mc,
                                                     float* __restrict__ logitsT) {
    __shared__ float smem[16384];  // 64 KB: staging overlay then sc/mc
    float (*stage_s)[65] = (float(*)[65])smem;          // 64x65
    float (*stage_m)[65] = (float(*)[65])(smem + 4160); // 64x65
    const int tid = threadIdx.x;
    const int v0 = blockIdx.x * 64;

    // cooperative coalesced load of the 64x64 v-tile, transposed into LDS
    for (int k = tid; k < 64 * EE; k += 256) {
        int vi = k >> 6, e = k & 63;   // lanes -> consecutive e: coalesced global
        float ls = log_sigma[(v0 + vi) * EE + e];
        ls = fminf(fmaxf(ls, LOG_SMIN), LOG_SMAX);
        stage_s[e][vi] = expf(ls);
        float m = mu[(v0 + vi) * EE + e];
        stage_m[e][vi] = fminf(fmaxf(m, -BOUND), BOUND);
    }
    __syncthreads();

    const int lane = tid & 63;
    const int wv   = tid >> 6;

    float sv[EE], mv[EE];
#pragma unroll
    for (int e = 0; e < EE; e++) { sv[e] = stage_s[e][lane]; mv[e] = stage_m[e][lane]; }
    __syncthreads();  // staging reads done; safe to overlay

    // overlay: sc/mc rows for all 128 topics
    float* scl = smem;          // 8192 floats
    float* mcl = smem + 8192;   // 8192 floats
    for (int i = tid; i < TT * EE; i += 256) {
        scl[i] = sc[i];
        mcl[i] = mc[i];
    }
    __syncthreads();

    for (int t = wv; t < TT; t += 4) {
        const float* __restrict__ srow = scl + t * EE;
        const float* __restrict__ mrow = mcl + t * EE;
        float acc_l2 = 0.0f;
        float q0 = 0.0f, q1 = 0.0f;
        float p0 = 1.0f, p1 = 1.0f;
#pragma unroll
        for (int g = 0; g < 16; g++) {
            float4 s4 = *(const float4*)(srow + g * 4);  // wave-uniform: broadcast
            float4 m4 = *(const float4*)(mrow + g * 4);
            int e = g * 4;
            float s, d;
            s = sv[e + 0] + s4.x; p0 *= s; d = mv[e + 0] - m4.x; q0 += d * d * __builtin_amdgcn_rcpf(s);
            s = sv[e + 1] + s4.y; p1 *= s; d = mv[e + 1] - m4.y; q1 += d * d * __builtin_amdgcn_rcpf(s);
            s = sv[e + 2] + s4.z; p0 *= s; d = mv[e + 2] - m4.z; q0 += d * d * __builtin_amdgcn_rcpf(s);
            s = sv[e + 3] + s4.w; p1 *= s; d = mv[e + 3] - m4.w; q1 += d * d * __builtin_amdgcn_rcpf(s);
            if ((g & 3) == 3) {  // 16 factors accumulated: s in [0.2,20] -> no overflow
                acc_l2 += __log2f(p0 * p1);
                p0 = 1.0f; p1 = 1.0f;
            }
        }
        float logit = -0.5f * (acc_l2 * LN2 + (q0 + q1) + E_LOG2PI);
        logitsT[t * VV + v0 + lane] = logit;
    }
}

// ---------------- kernel 2a: per-(topic, v-chunk) partial softmax stats ----------------
#define VCHUNK 4000  // VV / 8
__global__ __launch_bounds__(256) void stats_partial(const float* __restrict__ logitsT,
                                                     float* __restrict__ pm,
                                                     float* __restrict__ pl) {
    const int c = blockIdx.x;   // 0..7
    const int t = blockIdx.y;   // 0..127
    const int tid = threadIdx.x;
    const float* __restrict__ row = logitsT + (size_t)t * VV + c * VCHUNK;

    __shared__ float red_m[4];
    __shared__ float red_s[4];

    float m = -3.4e38f;
    for (int i = tid; i < VCHUNK; i += 256) m = fmaxf(m, row[i]);
#pragma unroll
    for (int off = 1; off < 64; off <<= 1) m = fmaxf(m, __shfl_xor(m, off));
    if ((tid & 63) == 0) red_m[tid >> 6] = m;
    __syncthreads();
    m = fmaxf(fmaxf(red_m[0], red_m[1]), fmaxf(red_m[2], red_m[3]));

    float s = 0.0f;
    for (int i = tid; i < VCHUNK; i += 256) s += __expf(row[i] - m);
#pragma unroll
    for (int off = 1; off < 64; off <<= 1) s += __shfl_xor(s, off);
    if ((tid & 63) == 0) red_s[tid >> 6] = s;
    __syncthreads();
    if (tid == 0) {
        pm[t * 8 + c] = m;
        pl[t * 8 + c] = red_s[0] + red_s[1] + red_s[2] + red_s[3];
    }
}

// ---------------- kernel 2b: merge chunk partials ----------------
__global__ __launch_bounds__(128) void stats_merge(const float* __restrict__ pm,
                                                   const float* __restrict__ pl,
                                                   float* __restrict__ stats) {
    int t = threadIdx.x;  // 128 threads, 1 block
    float m = -3.4e38f;
#pragma unroll
    for (int c = 0; c < 8; c++) m = fmaxf(m, pm[t * 8 + c]);
    float l = 0.0f;
#pragma unroll
    for (int c = 0; c < 8; c++) l += pl[t * 8 + c] * __expf(pm[t * 8 + c] - m);
    stats[t] = m;
    stats[TT + t] = 1.0f / l;
}

// ---------------- kernel 3: out[V,N] = softmax(logits) @ x  (bf16 MFMA) ----------------
// Block tile 64v x 128n; 4 waves, each wave = 32v x 64n = two 32x32x(K=128) chains.
// w computed on the fly (exp) into LDS [v][t-contig]; x transposed into LDS [n][t-contig].
// Rows padded to 136 (272 B = 17*16): 16B-aligned b128 reads, 4-way bank alias (cheap).
__global__ __launch_bounds__(256) void wx_mfma(const float* __restrict__ logitsT,
                                               const float* __restrict__ stats,
                                               const float* __restrict__ x,
                                               float* __restrict__ out) {
    __shared__ __attribute__((aligned(16))) unsigned short wlds[64][136];
    __shared__ __attribute__((aligned(16))) unsigned short xlds[128][136];
    __shared__ float slds[256];
    const int tid = threadIdx.x;
    const int v0 = blockIdx.x * 64;
    const int n0 = blockIdx.y * 128;

    slds[tid] = stats[tid];  // 256 floats: m_t then inv_l_t
    __syncthreads();

    {   // stage w: thread owns v = tid&63, t-range (tid>>6)*32..+32
        const int v = tid & 63;
        const int tg = tid >> 6;
        const float* __restrict__ lp = logitsT + v0 + v;
#pragma unroll
        for (int i = 0; i < 32; i += 2) {
            int t = tg * 32 + i;
            float lg0 = lp[(size_t)t * VV];        // lanes -> consecutive v: coalesced
            float lg1 = lp[(size_t)(t + 1) * VV];
            float w0 = __expf(lg0 - slds[t])     * slds[TT + t];
            float w1 = __expf(lg1 - slds[t + 1]) * slds[TT + t + 1];
            *(unsigned*)&wlds[v][t] = (unsigned)f2bf(w0) | ((unsigned)f2bf(w1) << 16);
        }
    }
    {   // stage x (transpose): thread owns n = tid&127, t-range (tid>>7)*64..+64
        const int n = tid & 127;
        const int tg = tid >> 7;
        const float* __restrict__ xp = x + n0 + n;
#pragma unroll
        for (int i = 0; i < 64; i += 2) {
            int t = tg * 64 + i;
            float x0 = xp[(size_t)t * NN];         // lanes -> consecutive n: coalesced
            float x1 = xp[(size_t)(t + 1) * NN];
            *(unsigned*)&xlds[n][t] = (unsigned)f2bf(x0) | ((unsigned)f2bf(x1) << 16);
        }
    }
    __syncthreads();

    const int lane = tid & 63;
    const int wv   = tid >> 6;
    const int vh   = (wv & 1) * 32;
    const int nh   = (wv >> 1) * 64;
    const int r32  = lane & 31;
    const int koff = (lane >> 5) * 8;

    float16 acc0 = {0,0,0,0,0,0,0,0,0,0,0,0,0,0,0,0};
    float16 acc1 = {0,0,0,0,0,0,0,0,0,0,0,0,0,0,0,0};
#pragma unroll
    for (int kb = 0; kb < 8; kb++) {
        short8 a  = *(const short8*)&wlds[vh + r32][kb * 16 + koff];
        short8 b0 = *(const short8*)&xlds[nh + r32][kb * 16 + koff];
        short8 b1 = *(const short8*)&xlds[nh + 32 + r32][kb * 16 + koff];
        acc0 = __builtin_amdgcn_mfma_f32_32x32x16_bf16(a, b0, acc0, 0, 0, 0);
        acc1 = __builtin_amdgcn_mfma_f32_32x32x16_bf16(a, b1, acc1, 0, 0, 0);
    }

    const int col = lane & 31;
    const int rbase = 4 * (lane >> 5);
#pragma unroll
    for (int r = 0; r < 16; r++) {
        int row = (r & 3) + 8 * (r >> 2) + rbase;  // measured C/D layout (32x32)
        float* dst = out + (size_t)(v0 + vh + row) * NN + n0 + nh + col;
        dst[0]  = acc0[r];
        dst[32] = acc1[r];
    }
}

extern "C" void kernel_launch(void* const* d_in, const int* in_sizes, int n_in,
                              void* d_out, int out_size, void* d_ws, size_t ws_size,
                              hipStream_t stream) {
    const float* x           = (const float*)d_in[0];  // [T,N]
    const float* mu          = (const float*)d_in[1];  // [V,E]
    const float* log_sigma   = (const float*)d_in[2];  // [V,E]
    const float* mu_c        = (const float*)d_in[3];  // [T,E]
    const float* log_sigma_c = (const float*)d_in[4];  // [T,E]
    float* out = (float*)d_out;

    // ws layout (floats): logitsT [T*V] | sc [T*E] | mc [T*E] | stats [2T] | pm [1024] | pl [1024]
    float* ws      = (float*)d_ws;
    float* logitsT = ws;
    float* sc      = ws + (size_t)TT * VV;
    float* mc      = sc + TT * EE;
    float* stats   = mc + TT * EE;
    float* pm      = stats + 2 * TT;
    float* pl      = pm + 1024;

    prep_ctx<<<(TT * EE + 255) / 256, 256, 0, stream>>>(mu_c, log_sigma_c, sc, mc);
    logits_kernel<<<VV / 64, 256, 0, stream>>>(mu, log_sigma, sc, mc, logitsT);
    stats_partial<<<dim3(8, TT), 256, 0, stream>>>(logitsT, pm, pl);
    stats_merge<<<1, 128, 0, stream>>>(pm, pl, stats);
    wx_mfma<<<dim3(VV / 64, NN / 128), 256, 0, stream>>>(logitsT, stats, x, out);
}